// Round 5
// baseline (401.434 us; speedup 1.0000x reference)
//
#include <hip/hip_runtime.h>
#include <hip/hip_bf16.h>
#include <math.h>

#define NROWS 131072   // B*T = 32*4096
#define KC    512      // codebook size
#define DD    64       // embedding dim
#define NELEM (NROWS * DD)

#define OUT_IDX_OFF  NELEM
#define OUT_LOSS_OFF (NELEM + NROWS)

// screen-side flag margin. Score = wn + 2 - 2*acc in (1.6, 2.4); packing
// clears 9 mantissa bits -> per-score perturbation < 512*ulp(2.4) = 1.22e-4.
// Pair bound: 2*1.22e-4 + 3e-5 (bf16 hi/lo screen error, validated at r0-r4)
// = 2.74e-4; margin 3.5e-4 gives 28% headroom. Over-flagging only costs
// refine time, never correctness.
#define MARGIN_P 3.5e-4f

// d_ws byte offsets
#define WSO_CNT   0                        // int   flagged-row count
#define WSO_DONE  4                        // int   refine blocks-done count
#define WSO_LOSS  8                        // float loss accumulator
#define WSO_WNORM 64                       // float wnorm_np[512]
#define WSO_BH    4096                     // bf16 frags W-hi: 32 tiles x 2 kh x 64 lanes x 8 = 64 KB
#define WSO_BL    (WSO_BH + 65536)         // bf16 frags W-lo: 64 KB
#define WSO_LIST  (WSO_BL + 65536)         // int flagList[NROWS]

typedef __attribute__((ext_vector_type(8))) short short8;
typedef __attribute__((ext_vector_type(4))) float f32x4;

// ---------------------------------------------------------------------------
// bf16 helpers (RNE via __float2bfloat16)
// ---------------------------------------------------------------------------
__device__ __forceinline__ short f2bf_bits(float f) {
  __hip_bfloat16 h = __float2bfloat16(f);
  short s; __builtin_memcpy(&s, &h, 2); return s;
}
__device__ __forceinline__ float bfbits2f(short s) {
  __hip_bfloat16 h; __builtin_memcpy(&h, &s, 2);
  return __bfloat162float(h);
}
// split 8 consecutive f32 into bf16 hi + bf16 lo(residual)
__device__ __forceinline__ void cvt8(const float* __restrict__ p, short8& hi, short8& lo) {
#pragma unroll
  for (int j = 0; j < 8; j++) {
    float f = p[j];
    short hb = f2bf_bits(f);
    float r = f - bfbits2f(hb);
    hi[j] = hb;
    lo[j] = f2bf_bits(r);
  }
}

__device__ __forceinline__ unsigned f_as_u(float f) {
  unsigned u; __builtin_memcpy(&u, &f, 4); return u;
}
__device__ __forceinline__ float u_as_f(unsigned u) {
  float f; __builtin_memcpy(&f, &u, 4); return f;
}

// ---------------------------------------------------------------------------
// numpy's pairwise sum of squares for 64 contiguous f32 (8-accumulator tree).
// contract(off) REQUIRED (hipcc default -ffp-contract=fast would fuse).
// ---------------------------------------------------------------------------
__device__ __forceinline__ float np_sumsq64(const float* __restrict__ p) {
#pragma clang fp contract(off)
  float r0 = p[0] * p[0], r1 = p[1] * p[1], r2 = p[2] * p[2], r3 = p[3] * p[3];
  float r4 = p[4] * p[4], r5 = p[5] * p[5], r6 = p[6] * p[6], r7 = p[7] * p[7];
  for (int i = 8; i < 64; i += 8) {
    r0 = r0 + p[i + 0] * p[i + 0];
    r1 = r1 + p[i + 1] * p[i + 1];
    r2 = r2 + p[i + 2] * p[i + 2];
    r3 = r3 + p[i + 3] * p[i + 3];
    r4 = r4 + p[i + 4] * p[i + 4];
    r5 = r5 + p[i + 5] * p[i + 5];
    r6 = r6 + p[i + 6] * p[i + 6];
    r7 = r7 + p[i + 7] * p[i + 7];
  }
  return ((r0 + r1) + (r2 + r3)) + ((r4 + r5) + (r6 + r7));
}

// ---------------------------------------------------------------------------
// Kernel 0: prep. (a) W -> MFMA-B-fragment-major bf16 hi/lo arrays.
// B[k=d][n=cw] fragment for 16x16x32: lane L holds B[(L>>4)*8+j][L&15], j=0..7.
// Element (tile t, khalf h, lane L, j) = W[cw = t*16+(L&15)][d = 32h+(L>>4)*8+j].
// (b) wnorm_np[k] = numpy-exact sum(W[k]^2).  (c) zero ws scalars.
// ---------------------------------------------------------------------------
__global__ void k_prep(const float* __restrict__ W, short8* __restrict__ Bh,
                       short8* __restrict__ Bl, float* __restrict__ wnorm,
                       int* __restrict__ flagCnt, int* __restrict__ doneCnt,
                       float* __restrict__ lossSum) {
  int gtid = blockIdx.x * blockDim.x + threadIdx.x;  // 0..4095
  if (gtid == 0) { *flagCnt = 0; *doneCnt = 0; *lossSum = 0.0f; }
  int t = gtid >> 7, rem = gtid & 127;
  int h = rem >> 6, L = rem & 63;
  int cw = (t << 4) + (L & 15);
  int dbase = (h << 5) + ((L >> 4) << 3);
  short8 hi, lo;
  cvt8(W + (cw << 6) + dbase, hi, lo);
  Bh[gtid] = hi;  // gtid == ((t*2+h)*64 + L)
  Bl[gtid] = lo;
  if (gtid < KC) wnorm[gtid] = np_sumsq64(W + (gtid << 6));
}

// ---------------------------------------------------------------------------
// Kernel 1: fused MFMA screen + argmin + epilogue.
// ROUND-5: attack the measured VALU floor (score/argmin update was ~49K
// cyc/CU = ~100% of observed VALUBusy) + remove k_prep_z's 19us.
//   - PACKED SORT-KEY ARGMIN: score s = wn + 2 - 2*acc is in (1.6,2.4) > 0,
//     so f32 bits order as u32. Key = (bits(s) & ~511) | k via one
//     v_and_or_b32. Update = {max,min,min}: 5 VALU/elem vs 6 with no index
//     cndmask, cheaper butterfly (min3-fusable), automatic lowest-k
//     tie-break. Near-ties within MARGIN_P (covers the 1.22e-4 packing
//     perturbation) are refined exactly - over-flagging is only refine time.
//   - A-frags rebuilt in-wave via cvt8 (r0-style; ~600cyc/wave). k_prep_z
//     DELETED (it cost ~19us of HBM round-trip).
//   - 256 thr (4 waves x 32 rows, MT=2, no K-split, no cross-wave merge);
//     B in LDS, 32KB pages x 4 phases -> 4 blocks/CU (128KB LDS).
//     launch_bounds(256,4): VGPR cap 128 vs ~100 footprint (r2 lesson:
//     never cap below footprint).
// ---------------------------------------------------------------------------
#define MT 2
#define ROWS_PER_WAVE 32
#define ROWS_PER_BLOCK 128   // 4 waves
#define SCREEN_THREADS 256
#define NPHASE 4
#define TPP 8                // codeword tiles per 32KB LDS page

__global__ __launch_bounds__(SCREEN_THREADS, 4) void k_screen(
    const float* __restrict__ z, const float* __restrict__ W,
    const short8* __restrict__ Bh, const short8* __restrict__ Bl,
    const float* __restrict__ wnorm, float* __restrict__ out,
    int* __restrict__ flagList, int* __restrict__ flagCnt,
    float* __restrict__ lossSum) {
  const int tid = threadIdx.x;
  const int lane = tid & 63;
  const int wave = tid >> 6;
  const int m = lane & 15, quad = lane >> 4;
  const int rowBase = blockIdx.x * ROWS_PER_BLOCK + wave * ROWS_PER_WAVE;

  __shared__ short8 sB[2048];  // 32 KB page: [hi: 1024 entries][lo: 1024]

  // ---- A fragments: zh/zl for 2 M-tiles x 2 k-halves, in-register ----
  short8 Ah[MT][2], Al[MT][2];
#pragma unroll
  for (int mt = 0; mt < MT; mt++) {
    const float* zp = z + (size_t)(rowBase + (mt << 4) + m) * DD + (quad << 3);
#pragma unroll
    for (int h = 0; h < 2; h++) cvt8(zp + (h << 5), Ah[mt][h], Al[mt][h]);
  }

  unsigned b1[MT][4], b2[MT][4];
#pragma unroll
  for (int mt = 0; mt < MT; mt++)
#pragma unroll
    for (int r = 0; r < 4; r++) { b1[mt][r] = 0xFFFFFFFFu; b2[mt][r] = 0xFFFFFFFFu; }

  for (int ph = 0; ph < NPHASE; ph++) {
    if (ph) __syncthreads();  // all waves done reading previous page
    // stage 32KB page: Bh entries [ph*1024,+1024) -> sB[0..1024), Bl -> +1024
#pragma unroll
    for (int c = 0; c < 4; c++) {
      const int i = (c << 8) + tid;
      sB[i] = Bh[(ph << 10) + i];
      sB[1024 + i] = Bl[(ph << 10) + i];
    }
    __syncthreads();

    // preload wn+2 for the page's 8 tiles (issued together, L1/L2-hot)
    float wn2[TPP];
#pragma unroll
    for (int tl = 0; tl < TPP; tl++)
      wn2[tl] = wnorm[((((ph << 3) + tl) << 4)) + m] + 2.0f;

#pragma unroll
    for (int tl = 0; tl < TPP; tl++) {
      short8 Bhf[2], Blf[2];
#pragma unroll
      for (int h = 0; h < 2; h++) {
        Bhf[h] = sB[(((tl << 1) + h) << 6) + lane];
        Blf[h] = sB[1024 + (((tl << 1) + h) << 6) + lane];
      }

      f32x4 acc[MT] = {{0.f, 0.f, 0.f, 0.f}, {0.f, 0.f, 0.f, 0.f}};
#pragma unroll
      for (int h = 0; h < 2; h++) {
#pragma unroll
        for (int mt = 0; mt < MT; mt++)
          acc[mt] = __builtin_amdgcn_mfma_f32_16x16x32_bf16(Ah[mt][h], Bhf[h], acc[mt], 0, 0, 0);
#pragma unroll
        for (int mt = 0; mt < MT; mt++)
          acc[mt] = __builtin_amdgcn_mfma_f32_16x16x32_bf16(Al[mt][h], Bhf[h], acc[mt], 0, 0, 0);
#pragma unroll
        for (int mt = 0; mt < MT; mt++)
          acc[mt] = __builtin_amdgcn_mfma_f32_16x16x32_bf16(Ah[mt][h], Blf[h], acc[mt], 0, 0, 0);
      }

      const unsigned kb = (unsigned)(((((ph << 3) + tl) << 4)) + m);
#pragma unroll
      for (int mt = 0; mt < MT; mt++)
#pragma unroll
        for (int r = 0; r < 4; r++) {
          float sf = fmaf(-2.0f, acc[mt][r], wn2[tl]);
          unsigned sp = (f_as_u(sf) & 0xFFFFFE00u) | kb;   // v_and_or_b32
          unsigned mx = b1[mt][r] > sp ? b1[mt][r] : sp;   // max(old b1, s)
          b2[mt][r] = b2[mt][r] < mx ? b2[mt][r] : mx;     // b2 = min(b2, mx)
          b1[mt][r] = b1[mt][r] < sp ? b1[mt][r] : sp;     // b1 = min(b1, s)
        }
    }
  }

  // ---- butterfly over 16 col-lanes (within quad group), u32 keys ----
#pragma unroll
  for (int off = 1; off < 16; off <<= 1) {
#pragma unroll
    for (int mt = 0; mt < MT; mt++)
#pragma unroll
      for (int r = 0; r < 4; r++) {
        unsigned o1 = (unsigned)__shfl_xor((int)b1[mt][r], off, 64);
        unsigned o2 = (unsigned)__shfl_xor((int)b2[mt][r], off, 64);
        unsigned mx = b1[mt][r] > o1 ? b1[mt][r] : o1;
        unsigned mn2 = b2[mt][r] < o2 ? b2[mt][r] : o2;
        b2[mt][r] = mn2 < mx ? mn2 : mx;                   // 2nd of union
        b1[mt][r] = b1[mt][r] < o1 ? b1[mt][r] : o1;
      }
  }

  // ---- epilogue: quad-parallel, shfl-free. Quad q owns rows mt*16+q*4+r;
  // its 16 lanes cover the 64 cols as f32x4. (b1,b2) quad-uniform. ----
  float lossAcc = 0.f;
#pragma unroll
  for (int mt = 0; mt < MT; mt++)
#pragma unroll
    for (int r = 0; r < 4; r++) {
      const int row = rowBase + (mt << 4) + (quad << 2) + r;
      const int ki = (int)(b1[mt][r] & 511u);
      f32x4 zv = *(const f32x4*)(z + (size_t)row * DD + (m << 2));
      f32x4 wv = *(const f32x4*)(W + (ki << 6) + (m << 2));
      f32x4 ov;
#pragma unroll
      for (int j = 0; j < 4; j++) {
        float tt = wv[j] - zv[j];
        ov[j] = zv[j] + tt;  // matches reference z + (z_q - z)
        float dl = zv[j] - ov[j];
        lossAcc = fmaf(dl, dl, lossAcc);
      }
      *(f32x4*)(out + (size_t)row * DD + (m << 2)) = ov;
      if (m == 0) {
        out[OUT_IDX_OFF + row] = (float)ki;
        float f1 = u_as_f(b1[mt][r] & 0xFFFFFE00u);
        float f2 = u_as_f(b2[mt][r] & 0xFFFFFE00u);
        if (f2 - f1 < MARGIN_P) {
          int slot = atomicAdd(flagCnt, 1);
          flagList[slot] = row;
        }
      }
    }

#pragma unroll
  for (int off = 1; off < 64; off <<= 1) lossAcc += __shfl_xor(lossAcc, off, 64);
  if (lane == 0) atomicAdd(lossSum, lossAcc);
}

// ---------------------------------------------------------------------------
// Kernel 2: numpy-f32 replication for flagged rows + patch out/loss.
// dist_np = fl32( fl32(A + wnp[k]) - fl32(2*C) ), C = f64 dot rounded once.
// Tail: last-block-done pattern finalizes the loss.
// ---------------------------------------------------------------------------
__global__ void k_refine(const float* __restrict__ z, const float* __restrict__ W,
                         const float* __restrict__ wnp, float* __restrict__ out,
                         const int* __restrict__ flagList,
                         const int* __restrict__ flagCnt,
                         float* __restrict__ lossSum, int* __restrict__ doneCnt) {
  int nflag = *flagCnt;
  int lane = threadIdx.x & 63;
  int wave = (blockIdx.x * blockDim.x + threadIdx.x) >> 6;
  int nWaves = (gridDim.x * blockDim.x) >> 6;

  for (int f = wave; f < nflag; f += nWaves) {
    int row = flagList[f];
    const float* zr = z + (size_t)row * DD;
    float A = np_sumsq64(zr);

    float best = 1e30f;
    int bk = 0x7fffffff;
#pragma unroll
    for (int j = 0; j < KC / 64; j++) {
      int k = lane + (j << 6);
      const float* wk = W + (k << 6);
      double cd = 0.0;
      for (int d = 0; d < DD; d++) cd = fma((double)zr[d], (double)wk[d], cd);
      float twoC = (float)(2.0 * cd);
      float dist;
      {
#pragma clang fp contract(off)
        float t1 = A + wnp[k];
        dist = t1 - twoC;
      }
      if (dist < best || (dist == best && k < bk)) { best = dist; bk = k; }
    }
#pragma unroll
    for (int off = 1; off < 64; off <<= 1) {
      float ov = __shfl_xor(best, off, 64);
      int ok = __shfl_xor(bk, off, 64);
      if (ov < best || (ov == best && ok < bk)) { best = ov; bk = ok; }
    }

    int kold = (int)out[OUT_IDX_OFF + row];
    if (bk != kold) {
      float zv = zr[lane];
      float wN = W[(bk << 6) + lane];
      float oOld = out[(size_t)row * DD + lane];
      float tN = wN - zv;
      float oN = zv + tN;
      out[(size_t)row * DD + lane] = oN;
      float dN = zv - oN, dO = zv - oOld;
      float delta = dN * dN - dO * dO;
#pragma unroll
      for (int off = 1; off < 64; off <<= 1) delta += __shfl_xor(delta, off, 64);
      if (lane == 0) {
        atomicAdd(lossSum, delta);
        out[OUT_IDX_OFF + row] = (float)bk;
      }
    }
  }

  // ---- finalize: last block to arrive writes the loss scalar ----
  __syncthreads();
  if (threadIdx.x == 0) {
    __threadfence();
    int d = atomicAdd(doneCnt, 1);
    if (d == (int)gridDim.x - 1) {
      float s = atomicAdd(lossSum, 0.0f);  // atomic read sees all prior adds
      out[OUT_LOSS_OFF] = 0.25f * s / (float)NELEM;
    }
  }
}

extern "C" void kernel_launch(void* const* d_in, const int* in_sizes, int n_in,
                              void* d_out, int out_size, void* d_ws, size_t ws_size,
                              hipStream_t stream) {
  const float* z = (const float*)d_in[0];
  const float* W = (const float*)d_in[1];
  float* out = (float*)d_out;
  char* ws = (char*)d_ws;

  int* flagCnt = (int*)(ws + WSO_CNT);
  int* doneCnt = (int*)(ws + WSO_DONE);
  float* lossSum = (float*)(ws + WSO_LOSS);
  float* wnorm = (float*)(ws + WSO_WNORM);
  short8* Bh = (short8*)(ws + WSO_BH);
  short8* Bl = (short8*)(ws + WSO_BL);
  int* flagList = (int*)(ws + WSO_LIST);

  k_prep<<<16, 256, 0, stream>>>(W, Bh, Bl, wnorm, flagCnt, doneCnt, lossSum);
  k_screen<<<NROWS / ROWS_PER_BLOCK, SCREEN_THREADS, 0, stream>>>(
      z, W, Bh, Bl, wnorm, out, flagList, flagCnt, lossSum);
  k_refine<<<256, 256, 0, stream>>>(z, W, wnorm, out, flagList, flagCnt,
                                    lossSum, doneCnt);
}

// Round 6
// 193.251 us; speedup vs baseline: 2.0773x; 2.0773x over previous
//
#include <hip/hip_runtime.h>
#include <hip/hip_bf16.h>
#include <math.h>

#define NROWS 131072   // B*T = 32*4096
#define KC    512      // codebook size
#define DD    64       // embedding dim
#define NELEM (NROWS * DD)

#define OUT_IDX_OFF  NELEM
#define OUT_LOSS_OFF (NELEM + NROWS)

#define MARGIN 3e-5f   // r0-validated: covers bf16 hi/lo screen error (~3e-6) with margin

// d_ws byte offsets
#define WSO_DONE  4                        // int   screen blocks-done count
#define WSO_LOSS  8                        // float loss accumulator
#define WSO_WNORM 64                       // float wnorm_np[512]
#define WSO_BH    4096                     // bf16 frags W-hi: 32 tiles x 2 kh x 64 lanes x 8 = 64 KB
#define WSO_BL    (WSO_BH + 65536)         // bf16 frags W-lo: 64 KB
#define WSO_WT    (WSO_BL + 65536)         // float Wt[64][512] transposed codebook, 128 KB

typedef __attribute__((ext_vector_type(8))) short short8;
typedef __attribute__((ext_vector_type(4))) float f32x4;

// ---------------------------------------------------------------------------
// bf16 helpers (RNE via __float2bfloat16)
// ---------------------------------------------------------------------------
__device__ __forceinline__ short f2bf_bits(float f) {
  __hip_bfloat16 h = __float2bfloat16(f);
  short s; __builtin_memcpy(&s, &h, 2); return s;
}
__device__ __forceinline__ float bfbits2f(short s) {
  __hip_bfloat16 h; __builtin_memcpy(&h, &s, 2);
  return __bfloat162float(h);
}
// split 8 consecutive f32 into bf16 hi + bf16 lo(residual)
__device__ __forceinline__ void cvt8(const float* __restrict__ p, short8& hi, short8& lo) {
#pragma unroll
  for (int j = 0; j < 8; j++) {
    float f = p[j];
    short hb = f2bf_bits(f);
    float r = f - bfbits2f(hb);
    hi[j] = hb;
    lo[j] = f2bf_bits(r);
  }
}

// ---------------------------------------------------------------------------
// numpy's pairwise sum of squares for 64 contiguous f32 (8-accumulator tree).
// contract(off) REQUIRED (hipcc default -ffp-contract=fast would fuse).
// ---------------------------------------------------------------------------
__device__ __forceinline__ float np_sumsq64(const float* __restrict__ p) {
#pragma clang fp contract(off)
  float r0 = p[0] * p[0], r1 = p[1] * p[1], r2 = p[2] * p[2], r3 = p[3] * p[3];
  float r4 = p[4] * p[4], r5 = p[5] * p[5], r6 = p[6] * p[6], r7 = p[7] * p[7];
  for (int i = 8; i < 64; i += 8) {
    r0 = r0 + p[i + 0] * p[i + 0];
    r1 = r1 + p[i + 1] * p[i + 1];
    r2 = r2 + p[i + 2] * p[i + 2];
    r3 = r3 + p[i + 3] * p[i + 3];
    r4 = r4 + p[i + 4] * p[i + 4];
    r5 = r5 + p[i + 5] * p[i + 5];
    r6 = r6 + p[i + 6] * p[i + 6];
    r7 = r7 + p[i + 7] * p[i + 7];
  }
  return ((r0 + r1) + (r2 + r3)) + ((r4 + r5) + (r6 + r7));
}

// ---------------------------------------------------------------------------
// Kernel 0: prep. (a) W -> MFMA-B-fragment-major bf16 hi/lo arrays.
// B[k=d][n=cw] fragment for 16x16x32: lane L holds B[(L>>4)*8+j][L&15], j=0..7.
// Element (tile t, khalf h, lane L, j) = W[cw = t*16+(L&15)][d = 32h+(L>>4)*8+j].
// (b) wnorm_np[k] = numpy-exact sum(W[k]^2).  (c) Wt[d][k] = W[k][d]
// (transposed copy so the refine dot reads lane-coalesced: r5 post-mortem
// showed the refine W-gather = 64 distinct cache lines per load).
// (d) zero ws scalars.
// ---------------------------------------------------------------------------
__global__ void k_prep(const float* __restrict__ W, short8* __restrict__ Bh,
                       short8* __restrict__ Bl, float* __restrict__ wnorm,
                       float* __restrict__ Wt,
                       int* __restrict__ doneCnt, float* __restrict__ lossSum) {
  int gtid = blockIdx.x * blockDim.x + threadIdx.x;  // 0..4095
  if (gtid == 0) { *doneCnt = 0; *lossSum = 0.0f; }
  int t = gtid >> 7, rem = gtid & 127;
  int h = rem >> 6, L = rem & 63;
  int cw = (t << 4) + (L & 15);
  int dbase = (h << 5) + ((L >> 4) << 3);
  short8 hi, lo;
  cvt8(W + (cw << 6) + dbase, hi, lo);
  Bh[gtid] = hi;  // gtid == ((t*2+h)*64 + L)
  Bl[gtid] = lo;
  if (gtid < KC) wnorm[gtid] = np_sumsq64(W + (gtid << 6));
  // transposed codebook: 32768 elements, 8 per thread, write-coalesced
#pragma unroll
  for (int c = 0; c < 8; c++) {
    int idx = (c << 12) + gtid;          // 0..32767
    int d = idx >> 9, k = idx & 511;
    Wt[idx] = W[(k << 6) + d];
  }
}

// ---------------------------------------------------------------------------
// Kernel 1: fused MFMA screen + argmin + epilogue + BLOCK-LOCAL refine +
// loss finalize. Main loop/geometry = round-0 VERBATIM (measured 93.5us:
// wave owns 64 rows, MT=4, B frags streamed from global (L2-hot), exact
// float b1/b2/bi argmin, margin 3e-5). New in round-6 (attacking the ~90us
// of r0's total that was NOT k_screen):
//   - flags are block-local -> flagged rows pushed to an LDS list and
//     refined AT THE END OF THIS KERNEL by the owning block (numpy-f32
//     exact path, identical fma order to the old k_refine, reading the
//     TRANSPOSED Wt so the dot's W loads are lane-coalesced instead of a
//     64-line gather).
//   - loss finalized via last-block-done tail (pattern validated r1-r5).
//   - pipeline is now 2 dispatches total (k_prep, k_screen).
// score_k = wnorm_np[k] - 2*(zh.wh + zl.wh + zh.wl)  [drops row-const
// ||z||^2; error <= ~3e-6 abs, covered by MARGIN].
// ---------------------------------------------------------------------------
#define MT 4
#define ROWS_PER_WAVE 64
#define ROWS_PER_BLOCK 256

__global__ __launch_bounds__(256) void k_screen(
    const float* __restrict__ z, const float* __restrict__ W,
    const short8* __restrict__ Bh, const short8* __restrict__ Bl,
    const float* __restrict__ wnorm, const float* __restrict__ Wt,
    float* __restrict__ out,
    float* __restrict__ lossSum, int* __restrict__ doneCnt) {
  const int tid = threadIdx.x;
  const int lane = tid & 63;
  const int wave = tid >> 6;
  const int rowBase = blockIdx.x * ROWS_PER_BLOCK + wave * ROWS_PER_WAVE;
  const int m = lane & 15, quad = lane >> 4;

  __shared__ int fcnt;
  __shared__ int fl[ROWS_PER_BLOCK];
  __shared__ float lw[4];
  if (tid == 0) fcnt = 0;

  // ---- A fragments: zh/zl for 4 M-tiles x 2 k-halves ----
  short8 Ah[MT][2], Al[MT][2];
#pragma unroll
  for (int mt = 0; mt < MT; mt++) {
    const float* zp = z + (size_t)(rowBase + (mt << 4) + m) * DD + (quad << 3);
#pragma unroll
    for (int h = 0; h < 2; h++) cvt8(zp + (h << 5), Ah[mt][h], Al[mt][h]);
  }
  __syncthreads();  // fcnt=0 visible before any epilogue push

  float b1[MT][4], b2[MT][4];
  int bi[MT][4];
#pragma unroll
  for (int mt = 0; mt < MT; mt++)
#pragma unroll
    for (int r = 0; r < 4; r++) { b1[mt][r] = 1e30f; b2[mt][r] = 1e30f; bi[mt][r] = 0; }

  // ---- main loop over 32 codeword tiles (r0 verbatim) ----
  for (int t = 0; t < 32; t++) {
    short8 Bhf[2], Blf[2];
#pragma unroll
    for (int h = 0; h < 2; h++) {
      Bhf[h] = Bh[((t * 2 + h) << 6) + lane];
      Blf[h] = Bl[((t * 2 + h) << 6) + lane];
    }
    float wn = wnorm[(t << 4) + m];

    f32x4 acc[4] = {{0.f, 0.f, 0.f, 0.f}, {0.f, 0.f, 0.f, 0.f},
                    {0.f, 0.f, 0.f, 0.f}, {0.f, 0.f, 0.f, 0.f}};
#pragma unroll
    for (int h = 0; h < 2; h++) {
#pragma unroll
      for (int mt = 0; mt < 4; mt++)
        acc[mt] = __builtin_amdgcn_mfma_f32_16x16x32_bf16(Ah[mt][h], Bhf[h], acc[mt], 0, 0, 0);
#pragma unroll
      for (int mt = 0; mt < 4; mt++)
        acc[mt] = __builtin_amdgcn_mfma_f32_16x16x32_bf16(Al[mt][h], Bhf[h], acc[mt], 0, 0, 0);
#pragma unroll
      for (int mt = 0; mt < 4; mt++)
        acc[mt] = __builtin_amdgcn_mfma_f32_16x16x32_bf16(Ah[mt][h], Blf[h], acc[mt], 0, 0, 0);
    }

    int colv = (t << 4) + m;
#pragma unroll
    for (int mt = 0; mt < 4; mt++)
#pragma unroll
      for (int r = 0; r < 4; r++) {
        float s = fmaf(-2.0f, acc[mt][r], wn);
        if (s < b1[mt][r]) { b2[mt][r] = b1[mt][r]; b1[mt][r] = s; bi[mt][r] = colv; }
        else b2[mt][r] = fminf(b2[mt][r], s);
      }
  }

  // ---- merge across the 16 col-lanes (xor butterfly within quad group) ----
#pragma unroll
  for (int off = 1; off < 16; off <<= 1) {
#pragma unroll
    for (int mt = 0; mt < 4; mt++)
#pragma unroll
      for (int r = 0; r < 4; r++) {
        float o1 = __shfl_xor(b1[mt][r], off, 64);
        float o2 = __shfl_xor(b2[mt][r], off, 64);
        int oi = __shfl_xor(bi[mt][r], off, 64);
        if (o1 < b1[mt][r] || (o1 == b1[mt][r] && oi < bi[mt][r])) {
          b2[mt][r] = fminf(b1[mt][r], o2);
          b1[mt][r] = o1; bi[mt][r] = oi;
        } else {
          b2[mt][r] = fminf(b2[mt][r], o1);
        }
      }
  }

  // ---- epilogue: quad-parallel, shfl-free (validated r1-r3).
  // Quad q owns rows (mt<<4)+q*4+r; its 16 lanes cover 64 cols as f32x4;
  // (b1,b2,bi) is uniform within each quad group after the butterfly. ----
  float lossAcc = 0.f;
#pragma unroll
  for (int mt = 0; mt < MT; mt++)
#pragma unroll
    for (int r = 0; r < 4; r++) {
      const int row = rowBase + (mt << 4) + (quad << 2) + r;
      const int ki = bi[mt][r];
      f32x4 zv = *(const f32x4*)(z + (size_t)row * DD + (m << 2));
      f32x4 wv = *(const f32x4*)(W + (ki << 6) + (m << 2));
      f32x4 ov;
#pragma unroll
      for (int j = 0; j < 4; j++) {
        float tt = wv[j] - zv[j];
        ov[j] = zv[j] + tt;  // matches reference z + (z_q - z)
        float dl = zv[j] - ov[j];
        lossAcc = fmaf(dl, dl, lossAcc);
      }
      *(f32x4*)(out + (size_t)row * DD + (m << 2)) = ov;
      if (m == 0) {
        out[OUT_IDX_OFF + row] = (float)ki;
        if (b2[mt][r] - b1[mt][r] < MARGIN) {
          int slot = atomicAdd(&fcnt, 1);
          fl[slot] = row;
        }
      }
    }

#pragma unroll
  for (int off = 1; off < 64; off <<= 1) lossAcc += __shfl_xor(lossAcc, off, 64);
  if (lane == 0) lw[wave] = lossAcc;
  __syncthreads();  // fl/fcnt + epilogue out-writes + lw visible block-wide
  if (tid == 0) atomicAdd(lossSum, (lw[0] + lw[1]) + (lw[2] + lw[3]));

  // ---- block-local refine: numpy-f32 replication for this block's flagged
  // rows. Same f64 fma chain order as the old k_refine (bit-identical);
  // W read through Wt -> lane-coalesced (k = lane+64j contiguous). ----
  const int nf = fcnt;
  for (int f = wave; f < nf; f += 4) {
    const int row = fl[f];
    const float* zr = z + (size_t)row * DD;
    float A = np_sumsq64(zr);

    float best = 1e30f;
    int bk = 0x7fffffff;
#pragma unroll
    for (int j = 0; j < KC / 64; j++) {
      int k = lane + (j << 6);
      double cd = 0.0;
      for (int d = 0; d < DD; d++)
        cd = fma((double)zr[d], (double)Wt[(d << 9) + k], cd);
      float twoC = (float)(2.0 * cd);
      float dist;
      {
#pragma clang fp contract(off)
        float t1 = A + wnorm[k];
        dist = t1 - twoC;
      }
      if (dist < best || (dist == best && k < bk)) { best = dist; bk = k; }
    }
#pragma unroll
    for (int off = 1; off < 64; off <<= 1) {
      float ov = __shfl_xor(best, off, 64);
      int ok = __shfl_xor(bk, off, 64);
      if (ov < best || (ov == best && ok < bk)) { best = ov; bk = ok; }
    }

    int kold = (int)out[OUT_IDX_OFF + row];
    if (bk != kold) {
      float zv = zr[lane];
      float wN = W[(bk << 6) + lane];
      float oOld = out[(size_t)row * DD + lane];
      float tN = wN - zv;
      float oN = zv + tN;
      out[(size_t)row * DD + lane] = oN;
      float dN = zv - oN, dO = zv - oOld;
      float delta = dN * dN - dO * dO;
#pragma unroll
      for (int off = 1; off < 64; off <<= 1) delta += __shfl_xor(delta, off, 64);
      if (lane == 0) {
        atomicAdd(lossSum, delta);
        out[OUT_IDX_OFF + row] = (float)bk;
      }
    }
  }

  // ---- finalize: last block to arrive writes the loss scalar ----
  __syncthreads();
  if (tid == 0) {
    __threadfence();
    int dnum = atomicAdd(doneCnt, 1);
    if (dnum == (int)gridDim.x - 1) {
      float s = atomicAdd(lossSum, 0.0f);  // atomic read sees all prior adds
      out[OUT_LOSS_OFF] = 0.25f * s / (float)NELEM;
    }
  }
}

extern "C" void kernel_launch(void* const* d_in, const int* in_sizes, int n_in,
                              void* d_out, int out_size, void* d_ws, size_t ws_size,
                              hipStream_t stream) {
  const float* z = (const float*)d_in[0];
  const float* W = (const float*)d_in[1];
  float* out = (float*)d_out;
  char* ws = (char*)d_ws;

  int* doneCnt = (int*)(ws + WSO_DONE);
  float* lossSum = (float*)(ws + WSO_LOSS);
  float* wnorm = (float*)(ws + WSO_WNORM);
  short8* Bh = (short8*)(ws + WSO_BH);
  short8* Bl = (short8*)(ws + WSO_BL);
  float* Wt = (float*)(ws + WSO_WT);

  k_prep<<<16, 256, 0, stream>>>(W, Bh, Bl, wnorm, Wt, doneCnt, lossSum);
  k_screen<<<NROWS / ROWS_PER_BLOCK, 256, 0, stream>>>(
      z, W, Bh, Bl, wnorm, Wt, out, lossSum, doneCnt);
}